// Round 4
// baseline (860.449 us; speedup 1.0000x reference)
//
#include <hip/hip_runtime.h>
#include <math.h>

#define N_ROWS 65536
#define ZDIM   256
#define KCODES 1024
#define IDX_OFF  (N_ROWS * ZDIM)        // 16777216
#define LOSS_OFF (IDX_OFF + N_ROWS)     // 16842752
#define ZQ_BLOCKS 2048
#define ZT_SZ (32 * 256)                // one z buffer (floats)
#define ET_SZ (32 * 260)                // one e buffer (floats, stride 260)

// ---------------- numpy-pairwise row sum of squares (256 cols) ----------------
__device__ __forceinline__ float np_pw128_sq(const float* __restrict__ p) {
    float r[8];
#pragma unroll
    for (int j = 0; j < 8; ++j) r[j] = __fmul_rn(p[j], p[j]);
    for (int i = 8; i < 128; i += 8) {
#pragma unroll
        for (int j = 0; j < 8; ++j)
            r[j] = __fadd_rn(r[j], __fmul_rn(p[i + j], p[i + j]));
    }
    float a = __fadd_rn(__fadd_rn(r[0], r[1]), __fadd_rn(r[2], r[3]));
    float b = __fadd_rn(__fadd_rn(r[4], r[5]), __fadd_rn(r[6], r[7]));
    return __fadd_rn(a, b);
}

__global__ void rowsq_kernel(const float* __restrict__ x, float* __restrict__ s, int nrows) {
    int r = blockIdx.x * blockDim.x + threadIdx.x;
    if (r >= nrows) return;
    const float* p = x + (size_t)r * ZDIM;
    s[r] = __fadd_rn(np_pw128_sq(p), np_pw128_sq(p + 128));
}

// ---------------- main distance + argmin kernel (v4) ----------------
// 256 threads, block tile 256 rows x 256 codes, thread tile 16x16 (acc 256).
// 32 phases p = ct*8+kc (ct: 4 code-tiles of 256, kc: 8 k-chunks of 32).
// Double-buffered LDS + reg-staged prefetch, ONE barrier per phase.
// Layouts (element (k,row)/(k,code), swz = ((k>>2)&7)<<2, all <=2-way banked):
//   zt: k*256 + (row ^ swz)
//   et: k*260 + (perm(c) ^ swz),  perm(c) = (c&3) + 4*(c>>4) + 64*((c>>2)&3)
// XOR touches bits 2-4 only -> b128 blocks contiguous/aligned; k-ascending
// fmaf chain per (row,code) preserved -> bit-exact vs np/OpenBLAS reference.
__global__ __launch_bounds__(256, 1) void argmin_kernel(
    const float* __restrict__ z, const float* __restrict__ e,
    const float* __restrict__ sz, const float* __restrict__ se,
    int* __restrict__ out_idx, float* __restrict__ out_idx_f) {
    __shared__ float zt[2 * ZT_SZ];     // 64 KB
    __shared__ float et[2 * ET_SZ];     // 65 KB
    __shared__ float sse[KCODES];       // 4 KB
    const int tid = threadIdx.x;
    const int tc = tid & 15;
    const int tr = tid >> 4;
    const int br0 = blockIdx.x * 256;

    // stage se once
    *(float4*)(sse + tid * 4) = *(const float4*)(se + tid * 4);

    float szr[16];
#pragma unroll
    for (int r = 0; r < 16; ++r) szr[r] = sz[br0 + tr * 16 + r];

    float bestd[16];
    int   besti[16];
#pragma unroll
    for (int r = 0; r < 16; ++r) { bestd[r] = __builtin_inff(); besti[r] = 0; }

    float4 zr[8], er[8];

    // ---- staging helpers (inlined via lambdas) ----
    auto loadZ = [&](int kc) {
#pragma unroll
        for (int it = 0; it < 8; ++it) {
            int flat = it * 256 + tid;
            int row = flat >> 3, q = flat & 7;
            zr[it] = *(const float4*)(z + (size_t)(br0 + row) * ZDIM + kc * 32 + q * 4);
        }
    };
    auto loadE = [&](int ct, int kc) {
#pragma unroll
        for (int it = 0; it < 8; ++it) {
            int flat = it * 256 + tid;
            int code = flat >> 3, q = flat & 7;
            er[it] = *(const float4*)(e + (size_t)(ct * 256 + code) * ZDIM + kc * 32 + q * 4);
        }
    };
    auto writeZ = [&](int buf) {
        float* ztb = zt + buf * ZT_SZ;
#pragma unroll
        for (int it = 0; it < 8; ++it) {
            int flat = it * 256 + tid;
            int row = flat >> 3, q = flat & 7;
            int dst = row ^ (q << 2);
            ztb[(q * 4 + 0) * 256 + dst] = zr[it].x;
            ztb[(q * 4 + 1) * 256 + dst] = zr[it].y;
            ztb[(q * 4 + 2) * 256 + dst] = zr[it].z;
            ztb[(q * 4 + 3) * 256 + dst] = zr[it].w;
        }
    };
    auto writeE = [&](int buf) {
        float* etb = et + buf * ET_SZ;
#pragma unroll
        for (int it = 0; it < 8; ++it) {
            int flat = it * 256 + tid;
            int code = flat >> 3, q = flat & 7;
            int pc = (code & 3) + ((code >> 4) << 2) + (((code >> 2) & 3) << 6);
            int dst = pc ^ (q << 2);
            etb[(q * 4 + 0) * 260 + dst] = er[it].x;
            etb[(q * 4 + 1) * 260 + dst] = er[it].y;
            etb[(q * 4 + 2) * 260 + dst] = er[it].z;
            etb[(q * 4 + 3) * 260 + dst] = er[it].w;
        }
    };

    // prologue: stage phase 0 into buffer 0
    loadZ(0);
    loadE(0, 0);
    writeZ(0);
    writeE(0);
    __syncthreads();

    float acc[16][16];

#pragma unroll 1
    for (int p = 0; p < 32; ++p) {
        const int buf = p & 1;
        const int ct = p >> 3;
        const int kc = p & 7;
        if (kc == 0) {
#pragma unroll
            for (int r = 0; r < 16; ++r)
#pragma unroll
                for (int c = 0; c < 16; ++c) acc[r][c] = 0.0f;
        }
        // prefetch next phase into regs (overlaps with compute below)
        if (p < 31) {
            const int pn = p + 1;
            loadZ(pn & 7);
            loadE(pn >> 3, pn & 7);
        }
        // compute current phase from buf
        {
            const float* ztb = zt + buf * ZT_SZ;
            const float* etb = et + buf * ET_SZ;
#pragma unroll 1
            for (int g4 = 0; g4 < 8; ++g4) {
                const int swz = g4 << 2;
#pragma unroll
                for (int kk = 0; kk < 4; ++kk) {
                    const int k = g4 * 4 + kk;
                    const float* zrow = ztb + k * 256;
                    const float* erow = etb + k * 260;
                    float4 zA = *(const float4*)(zrow + ((tr * 16 + 0) ^ swz));
                    float4 zB = *(const float4*)(zrow + ((tr * 16 + 4) ^ swz));
                    float4 zC = *(const float4*)(zrow + ((tr * 16 + 8) ^ swz));
                    float4 zD = *(const float4*)(zrow + ((tr * 16 + 12) ^ swz));
                    const int eb = (tc << 2) ^ swz;
                    float4 e0 = *(const float4*)(erow + eb);
                    float4 e1 = *(const float4*)(erow + eb + 64);
                    float4 e2 = *(const float4*)(erow + eb + 128);
                    float4 e3 = *(const float4*)(erow + eb + 192);
                    float zf[16] = {zA.x, zA.y, zA.z, zA.w, zB.x, zB.y, zB.z, zB.w,
                                    zC.x, zC.y, zC.z, zC.w, zD.x, zD.y, zD.z, zD.w};
                    float ef[16] = {e0.x, e0.y, e0.z, e0.w, e1.x, e1.y, e1.z, e1.w,
                                    e2.x, e2.y, e2.z, e2.w, e3.x, e3.y, e3.z, e3.w};
#pragma unroll
                    for (int r = 0; r < 16; ++r)
#pragma unroll
                        for (int c = 0; c < 16; ++c)
                            acc[r][c] = fmaf(zf[r], ef[c], acc[r][c]);
                }
            }
        }
        // write prefetched regs into the other buffer
        if (p < 31) {
            writeZ(buf ^ 1);
            writeE(buf ^ 1);
        }
        // epilogue at end of each code tile (codes ascending; strict < = first)
        if (kc == 7) {
#pragma unroll
            for (int j = 0; j < 16; ++j) {
                int code = ct * 256 + tc * 16 + j;
                float sec = sse[code];
#pragma unroll
                for (int r = 0; r < 16; ++r) {
                    float t = __fadd_rn(szr[r], sec);
                    float d = __fsub_rn(t, 2.0f * acc[r][j]);
                    if (d < bestd[r]) { bestd[r] = d; besti[r] = code; }
                }
            }
        }
        __syncthreads();
    }

    // cross-thread reduction: lexicographic (d, idx) min == first-occurrence
    float2* red = (float2*)zt;   // 256 rows * 16 = 4096 float2 = 32 KB (buf 0)
#pragma unroll
    for (int r = 0; r < 16; ++r)
        red[(tr * 16 + r) * 16 + tc] = make_float2(bestd[r], (float)besti[r]);
    __syncthreads();
    {
        float bd = __builtin_inff();
        float bi = 0.0f;
        for (int t = 0; t < 16; ++t) {
            float2 v = red[tid * 16 + t];
            if (v.x < bd || (v.x == bd && v.y < bi)) { bd = v.x; bi = v.y; }
        }
        out_idx[br0 + tid]   = (int)bi;
        out_idx_f[br0 + tid] = bi;
    }
}

// ---------------- z_q_st + loss partial (no atomics) ----------------
__global__ __launch_bounds__(256) void zq_loss_kernel(
    const float* __restrict__ z, const float* __restrict__ e,
    const int* __restrict__ idx, float* __restrict__ out,
    double* __restrict__ partial) {
    const int tid = threadIdx.x;
    const int rl  = tid >> 6;
    const int ln  = tid & 63;
    const int row0 = blockIdx.x * 32;

    float acc = 0.0f;
#pragma unroll
    for (int it = 0; it < 8; ++it) {
        int row = row0 + it * 4 + rl;
        int code = idx[row];
        const float4 vz = *(const float4*)(z + (size_t)row  * ZDIM + ln * 4);
        const float4 vq = *(const float4*)(e + (size_t)code * ZDIM + ln * 4);
        float4 o;
        float dx = __fsub_rn(vq.x, vz.x);
        float dy = __fsub_rn(vq.y, vz.y);
        float dz_ = __fsub_rn(vq.z, vz.z);
        float dw = __fsub_rn(vq.w, vz.w);
        o.x = __fadd_rn(vz.x, dx);
        o.y = __fadd_rn(vz.y, dy);
        o.z = __fadd_rn(vz.z, dz_);
        o.w = __fadd_rn(vz.w, dw);
        *(float4*)(out + (size_t)row * ZDIM + ln * 4) = o;
        acc = __fadd_rn(acc, __fmul_rn(dx, dx));
        acc = __fadd_rn(acc, __fmul_rn(dy, dy));
        acc = __fadd_rn(acc, __fmul_rn(dz_, dz_));
        acc = __fadd_rn(acc, __fmul_rn(dw, dw));
    }

    __shared__ double red[256];
    red[tid] = (double)acc;
    __syncthreads();
#pragma unroll
    for (int s = 128; s > 0; s >>= 1) {
        if (tid < s) red[tid] += red[tid + s];
        __syncthreads();
    }
    if (tid == 0) partial[blockIdx.x] = red[0];
}

__global__ __launch_bounds__(256) void loss_final_kernel(
    const double* __restrict__ partial, float* __restrict__ out_loss) {
    const int tid = threadIdx.x;
    double s = 0.0;
    for (int i = tid; i < ZQ_BLOCKS; i += 256) s += partial[i];
    __shared__ double red[256];
    red[tid] = s;
    __syncthreads();
#pragma unroll
    for (int st = 128; st > 0; st >>= 1) {
        if (tid < st) red[tid] += red[tid + st];
        __syncthreads();
    }
    if (tid == 0) {
        double M = red[0] / 16777216.0;
        float m32 = (float)M;
        out_loss[0] = __fadd_rn(m32, __fmul_rn(0.25f, m32));
    }
}

extern "C" void kernel_launch(void* const* d_in, const int* in_sizes, int n_in,
                              void* d_out, int out_size, void* d_ws, size_t ws_size,
                              hipStream_t stream) {
    const float* z = (const float*)d_in[0];
    const float* e = (const float*)d_in[1];
    float* out = (float*)d_out;
    char* ws = (char*)d_ws;

    double* partial = (double*)ws;
    float*  sz   = (float*)(ws + ZQ_BLOCKS * sizeof(double));
    float*  se   = (float*)(ws + ZQ_BLOCKS * sizeof(double) + (size_t)N_ROWS * 4);
    int*    idx  = (int*)  (ws + ZQ_BLOCKS * sizeof(double) + (size_t)N_ROWS * 4 + (size_t)KCODES * 4);

    rowsq_kernel<<<N_ROWS / 256, 256, 0, stream>>>(z, sz, N_ROWS);
    rowsq_kernel<<<KCODES / 256, 256, 0, stream>>>(e, se, KCODES);
    argmin_kernel<<<N_ROWS / 256, 256, 0, stream>>>(z, e, sz, se, idx, out + IDX_OFF);
    zq_loss_kernel<<<ZQ_BLOCKS, 256, 0, stream>>>(z, e, idx, out, partial);
    loss_final_kernel<<<1, 256, 0, stream>>>(partial, out + LOSS_OFF);
}